// Round 1
// baseline (502.440 us; speedup 1.0000x reference)
//
#include <hip/hip_runtime.h>
#include <hip/hip_bf16.h>

#define B_  2
#define L_  2048
#define D_  1024
#define H_  16
#define HD_ 64

typedef __bf16 bf16x8 __attribute__((ext_vector_type(8)));
typedef float  f32x4  __attribute__((ext_vector_type(4)));
using bf16_t = __hip_bfloat16;

static __device__ __forceinline__ f32x4 mfma16(bf16x8 a, bf16x8 b, f32x4 c) {
    return __builtin_amdgcn_mfma_f32_16x16x32_bf16(a, b, c, 0, 0, 0);
}

// ---- fp32 -> bf16 elementwise convert (x) ----
__global__ __launch_bounds__(256) void k_convert(const float* __restrict__ in,
                                                 bf16_t* __restrict__ out, int n8) {
    int idx = blockIdx.x * 256 + threadIdx.x;
    if (idx >= n8) return;
    const float4* p = (const float4*)in + (size_t)idx * 2;
    float4 a = p[0], b = p[1];
    union { bf16_t h[8]; bf16x8 v; } u;
    u.h[0] = __float2bfloat16(a.x); u.h[1] = __float2bfloat16(a.y);
    u.h[2] = __float2bfloat16(a.z); u.h[3] = __float2bfloat16(a.w);
    u.h[4] = __float2bfloat16(b.x); u.h[5] = __float2bfloat16(b.y);
    u.h[6] = __float2bfloat16(b.z); u.h[7] = __float2bfloat16(b.w);
    *(bf16x8*)(out + (size_t)idx * 8) = u.v;
}

// ---- fp32 W[k][n] -> bf16 Wt[n][k] (LDS-tiled transpose+convert) ----
__global__ __launch_bounds__(256) void k_transpose(const float* __restrict__ w,
                                                   bf16_t* __restrict__ wt) {
    __shared__ bf16_t tile[64][65];
    int t  = threadIdx.x;
    int kb = blockIdx.x * 64, nb = blockIdx.y * 64;
    int r  = t >> 4, c4 = (t & 15) * 4;
    #pragma unroll
    for (int it = 0; it < 4; ++it) {
        int kr = r + it * 16;
        float4 v = *(const float4*)&w[(size_t)(kb + kr) * D_ + nb + c4];
        tile[kr][c4 + 0] = __float2bfloat16(v.x);
        tile[kr][c4 + 1] = __float2bfloat16(v.y);
        tile[kr][c4 + 2] = __float2bfloat16(v.z);
        tile[kr][c4 + 3] = __float2bfloat16(v.w);
    }
    __syncthreads();
    #pragma unroll
    for (int it = 0; it < 4; ++it) {
        int nr = r + it * 16;
        union { bf16_t h[4]; unsigned long long u; } o;
        o.h[0] = tile[c4 + 0][nr];
        o.h[1] = tile[c4 + 1][nr];
        o.h[2] = tile[c4 + 2][nr];
        o.h[3] = tile[c4 + 3][nr];
        *(unsigned long long*)&wt[(size_t)(nb + nr) * D_ + kb + c4] = o.u;
    }
}

// ---- bf16 GEMM: C[M=4096][N=1024] = A[M][K] @ W[K][N] + bias, W given as Wt[n][k]
// MODE 0: store bf16 to [B,H,L,HD] (Q/K)   MODE 1: store bf16 to [B,H,HD,L] (V^T)
// MODE 2: store fp32 row-major to d_out (final projection)
template <int MODE>
__global__ __launch_bounds__(256) void k_gemm(const bf16_t* __restrict__ A,
                                              const bf16_t* __restrict__ Wt,
                                              const float* __restrict__ bias,
                                              void* __restrict__ outp) {
    __shared__ __align__(16) bf16_t Al[128][32];
    __shared__ __align__(16) bf16_t Bl[128][32];
    const int K = D_;
    int tid = threadIdx.x, lane = tid & 63, wid = tid >> 6;
    int m0 = blockIdx.y * 128, n0 = blockIdx.x * 128;
    int wm = (wid >> 1) * 64, wn = (wid & 1) * 64;
    int r16 = lane & 15, g = lane >> 4;
    int srow = tid >> 2, sch = (tid & 3) * 8;
    f32x4 acc[4][4] = {};
    for (int kb = 0; kb < K; kb += 32) {
        __syncthreads();
        *(bf16x8*)&Al[srow][sch]      = *(const bf16x8*)&A [(size_t)(m0 + srow) * K + kb + sch];
        *(bf16x8*)&Al[srow + 64][sch] = *(const bf16x8*)&A [(size_t)(m0 + srow + 64) * K + kb + sch];
        *(bf16x8*)&Bl[srow][sch]      = *(const bf16x8*)&Wt[(size_t)(n0 + srow) * K + kb + sch];
        *(bf16x8*)&Bl[srow + 64][sch] = *(const bf16x8*)&Wt[(size_t)(n0 + srow + 64) * K + kb + sch];
        __syncthreads();
        bf16x8 af[4], bfr[4];
        #pragma unroll
        for (int i = 0; i < 4; ++i) af[i]  = *(const bf16x8*)&Al[wm + i * 16 + r16][g * 8];
        #pragma unroll
        for (int j = 0; j < 4; ++j) bfr[j] = *(const bf16x8*)&Bl[wn + j * 16 + r16][g * 8];
        #pragma unroll
        for (int i = 0; i < 4; ++i)
            #pragma unroll
            for (int j = 0; j < 4; ++j)
                acc[i][j] = mfma16(af[i], bfr[j], acc[i][j]);
    }
    #pragma unroll
    for (int i = 0; i < 4; ++i) {
        #pragma unroll
        for (int j = 0; j < 4; ++j) {
            int n = n0 + wn + j * 16 + r16;
            float bv = bias[n];
            #pragma unroll
            for (int e = 0; e < 4; ++e) {
                int m = m0 + wm + i * 16 + g * 4 + e;
                float v = acc[i][j][e] + bv;
                if (MODE == 2) {
                    ((float*)outp)[(size_t)m * D_ + n] = v;
                } else {
                    int b = m >> 11, l = m & (L_ - 1);
                    int h = n >> 6, hd = n & 63;
                    bf16_t* o = (bf16_t*)outp;
                    if (MODE == 0)
                        o[(((size_t)(b * H_ + h)) * L_ + l) * HD_ + hd] = __float2bfloat16(v);
                    else
                        o[(((size_t)(b * H_ + h)) * HD_ + hd) * L_ + l] = __float2bfloat16(v);
                }
            }
        }
    }
}

// ---- fused causal attention: writes attn (fp32, normalized) and ctx (bf16) ----
// one wave = one (b,h, 16-row q-tile). Phase1: Z + unnormalized PV. Phase2: write attn.
__global__ __launch_bounds__(256) void k_attn(const bf16_t* __restrict__ Q,
                                              const bf16_t* __restrict__ Kb,
                                              const bf16_t* __restrict__ VT,
                                              bf16_t* __restrict__ ctx,
                                              float* __restrict__ attn) {
    __shared__ __align__(16) bf16_t plds[4][16][32];
    int tid = threadIdx.x, lane = tid & 63, wid = tid >> 6;
    int task = blockIdx.x * 4 + wid;
    int qt = task & 127, bh = task >> 7;
    int b = bh >> 4, h = bh & 15;
    int qb = qt * 16;
    const bf16_t* Qh = Q  + (size_t)bh * L_ * HD_;
    const bf16_t* Kh = Kb + (size_t)bh * L_ * HD_;
    const bf16_t* Vh = VT + (size_t)bh * HD_ * L_;
    int r16 = lane & 15, g = lane >> 4;
    bf16x8 q0 = *(const bf16x8*)&Qh[(qb + r16) * HD_ + g * 8];
    bf16x8 q1 = *(const bf16x8*)&Qh[(qb + r16) * HD_ + 32 + g * 8];
    f32x4 ctxa[4] = {};
    float z[4] = {0.f, 0.f, 0.f, 0.f};
    const int diag_kt = (qb + 15) >> 5;
    const float scale = 0.125f;

    // phase 1: Z + unnormalized context
    for (int kt = 0; kt <= diag_kt; ++kt) {
        int kb = kt * 32;
        #pragma unroll
        for (int s = 0; s < 2; ++s) {
            bf16x8 kf0 = *(const bf16x8*)&Kh[(kb + s * 16 + r16) * HD_ + g * 8];
            bf16x8 kf1 = *(const bf16x8*)&Kh[(kb + s * 16 + r16) * HD_ + 32 + g * 8];
            f32x4 sa = {};
            sa = mfma16(q0, kf0, sa);
            sa = mfma16(q1, kf1, sa);
            #pragma unroll
            for (int e = 0; e < 4; ++e) {
                int qrow = qb + g * 4 + e;
                int key = kb + s * 16 + r16;
                float sc = sa[e] * scale;
                sc = fminf(fmaxf(sc, -50.f), 50.f);
                float ev = (key > qrow) ? 0.f : __expf(sc);
                z[e] += ev;
                plds[wid][g * 4 + e][s * 16 + r16] = __float2bfloat16(ev);
            }
        }
        bf16x8 pa = *(const bf16x8*)&plds[wid][r16][g * 8];
        #pragma unroll
        for (int t = 0; t < 4; ++t) {
            bf16x8 vf = *(const bf16x8*)&Vh[(t * 16 + r16) * L_ + kb + g * 8];
            ctxa[t] = mfma16(pa, vf, ctxa[t]);
        }
    }

    // reduce Z across the 16 lanes of each row-group
    float invz[4];
    #pragma unroll
    for (int e = 0; e < 4; ++e) {
        float v = z[e];
        v += __shfl_xor(v, 1);
        v += __shfl_xor(v, 2);
        v += __shfl_xor(v, 4);
        v += __shfl_xor(v, 8);
        invz[e] = 1.f / v;
    }

    // normalized context -> ctx buffer [B, L, D] bf16
    #pragma unroll
    for (int t = 0; t < 4; ++t)
        #pragma unroll
        for (int e = 0; e < 4; ++e) {
            int qrow = qb + g * 4 + e;
            int col = h * HD_ + t * 16 + r16;
            ctx[((size_t)b * L_ + qrow) * D_ + col] = __float2bfloat16(ctxa[t][e] * invz[e]);
        }

    // phase 2: recompute scores, write normalized attn
    for (int kt = 0; kt <= diag_kt; ++kt) {
        int kb = kt * 32;
        #pragma unroll
        for (int s = 0; s < 2; ++s) {
            bf16x8 kf0 = *(const bf16x8*)&Kh[(kb + s * 16 + r16) * HD_ + g * 8];
            bf16x8 kf1 = *(const bf16x8*)&Kh[(kb + s * 16 + r16) * HD_ + 32 + g * 8];
            f32x4 sa = {};
            sa = mfma16(q0, kf0, sa);
            sa = mfma16(q1, kf1, sa);
            #pragma unroll
            for (int e = 0; e < 4; ++e) {
                int qrow = qb + g * 4 + e;
                int key = kb + s * 16 + r16;
                float sc = sa[e] * scale;
                sc = fminf(fmaxf(sc, -50.f), 50.f);
                float av = (key > qrow) ? 0.f : __expf(sc) * invz[e];
                attn[((size_t)bh * L_ + qrow) * L_ + key] = av;
            }
        }
    }

    // zero-fill the fully-masked tail of each row
    int zstart = (diag_kt + 1) * 32;
    float4 zero4 = make_float4(0.f, 0.f, 0.f, 0.f);
    for (int r = 0; r < 16; ++r) {
        size_t rowbase = ((size_t)bh * L_ + qb + r) * L_;
        for (int c = zstart + lane * 4; c < L_; c += 256) {
            *(float4*)&attn[rowbase + c] = zero4;
        }
    }
}

extern "C" void kernel_launch(void* const* d_in, const int* in_sizes, int n_in,
                              void* d_out, int out_size, void* d_ws, size_t ws_size,
                              hipStream_t stream) {
    const float* x  = (const float*)d_in[0];
    const float* wq = (const float*)d_in[1];
    const float* bq = (const float*)d_in[2];
    const float* wk = (const float*)d_in[3];
    const float* bk = (const float*)d_in[4];
    const float* wv = (const float*)d_in[5];
    const float* bv = (const float*)d_in[6];
    const float* wo = (const float*)d_in[7];
    const float* bo = (const float*)d_in[8];

    char* ws = (char*)d_ws;
    bf16_t* xb   = (bf16_t*)(ws);
    bf16_t* wqt  = (bf16_t*)(ws + ( 8u << 20));
    bf16_t* wkt  = (bf16_t*)(ws + (10u << 20));
    bf16_t* wvt  = (bf16_t*)(ws + (12u << 20));
    bf16_t* wot  = (bf16_t*)(ws + (14u << 20));
    bf16_t* Qb   = (bf16_t*)(ws + (16u << 20));
    bf16_t* Kbuf = (bf16_t*)(ws + (24u << 20));
    bf16_t* VTb  = (bf16_t*)(ws + (32u << 20));
    bf16_t* ctxb = (bf16_t*)(ws + (40u << 20));

    float* out  = (float*)d_out;
    float* attn = out + (size_t)B_ * L_ * D_;

    k_convert<<<2048, 256, 0, stream>>>(x, xb, (B_ * L_ * D_) / 8);
    dim3 tg(16, 16);
    k_transpose<<<tg, 256, 0, stream>>>(wq, wqt);
    k_transpose<<<tg, 256, 0, stream>>>(wk, wkt);
    k_transpose<<<tg, 256, 0, stream>>>(wv, wvt);
    k_transpose<<<tg, 256, 0, stream>>>(wo, wot);

    dim3 gg(D_ / 128, (B_ * L_) / 128);
    k_gemm<0><<<gg, 256, 0, stream>>>(xb, wqt, bq, Qb);
    k_gemm<0><<<gg, 256, 0, stream>>>(xb, wkt, bk, Kbuf);
    k_gemm<1><<<gg, 256, 0, stream>>>(xb, wvt, bv, VTb);

    k_attn<<<1024, 256, 0, stream>>>(Qb, Kbuf, VTb, ctxb, attn);

    k_gemm<2><<<gg, 256, 0, stream>>>(ctxb, wot, bo, d_out);
}

// Round 2
// 364.794 us; speedup vs baseline: 1.3773x; 1.3773x over previous
//
#include <hip/hip_runtime.h>
#include <hip/hip_bf16.h>

#define B_  2
#define L_  2048
#define D_  1024
#define H_  16
#define HD_ 64

typedef __bf16 bf16x8 __attribute__((ext_vector_type(8)));
typedef float  f32x4  __attribute__((ext_vector_type(4)));
using bf16_t = __hip_bfloat16;

static __device__ __forceinline__ f32x4 mfma16(bf16x8 a, bf16x8 b, f32x4 c) {
    return __builtin_amdgcn_mfma_f32_16x16x32_bf16(a, b, c, 0, 0, 0);
}

// ---- fp32 -> bf16 elementwise convert (x) ----
__global__ __launch_bounds__(256) void k_convert(const float* __restrict__ in,
                                                 bf16_t* __restrict__ out, int n8) {
    int idx = blockIdx.x * 256 + threadIdx.x;
    if (idx >= n8) return;
    const float4* p = (const float4*)in + (size_t)idx * 2;
    float4 a = p[0], b = p[1];
    union { bf16_t h[8]; bf16x8 v; } u;
    u.h[0] = __float2bfloat16(a.x); u.h[1] = __float2bfloat16(a.y);
    u.h[2] = __float2bfloat16(a.z); u.h[3] = __float2bfloat16(a.w);
    u.h[4] = __float2bfloat16(b.x); u.h[5] = __float2bfloat16(b.y);
    u.h[6] = __float2bfloat16(b.z); u.h[7] = __float2bfloat16(b.w);
    *(bf16x8*)(out + (size_t)idx * 8) = u.v;
}

// ---- fp32 W[k][n] -> bf16 Wt[n][k] (LDS-tiled transpose+convert) ----
__global__ __launch_bounds__(256) void k_transpose(const float* __restrict__ w,
                                                   bf16_t* __restrict__ wt) {
    __shared__ bf16_t tile[64][65];
    int t  = threadIdx.x;
    int kb = blockIdx.x * 64, nb = blockIdx.y * 64;
    int r  = t >> 4, c4 = (t & 15) * 4;
    #pragma unroll
    for (int it = 0; it < 4; ++it) {
        int kr = r + it * 16;
        float4 v = *(const float4*)&w[(size_t)(kb + kr) * D_ + nb + c4];
        tile[kr][c4 + 0] = __float2bfloat16(v.x);
        tile[kr][c4 + 1] = __float2bfloat16(v.y);
        tile[kr][c4 + 2] = __float2bfloat16(v.z);
        tile[kr][c4 + 3] = __float2bfloat16(v.w);
    }
    __syncthreads();
    #pragma unroll
    for (int it = 0; it < 4; ++it) {
        int nr = r + it * 16;
        union { bf16_t h[4]; unsigned long long u; } o;
        o.h[0] = tile[c4 + 0][nr];
        o.h[1] = tile[c4 + 1][nr];
        o.h[2] = tile[c4 + 2][nr];
        o.h[3] = tile[c4 + 3][nr];
        *(unsigned long long*)&wt[(size_t)(nb + nr) * D_ + kb + c4] = o.u;
    }
}

// ---- bf16 GEMM: C[M=4096][N=1024] = A[M][K] @ W[K][N] + bias, W given as Wt[n][k]
// MODE 0: store bf16 to [B,H,L,HD] (Q/K)   MODE 1: store bf16 to [B,H,HD,L] (V^T)
// MODE 2: store fp32 row-major to d_out (final projection)
template <int MODE>
__global__ __launch_bounds__(256) void k_gemm(const bf16_t* __restrict__ A,
                                              const bf16_t* __restrict__ Wt,
                                              const float* __restrict__ bias,
                                              void* __restrict__ outp) {
    __shared__ __align__(16) bf16_t Al[128][32];
    __shared__ __align__(16) bf16_t Bl[128][32];
    const int K = D_;
    int tid = threadIdx.x, lane = tid & 63, wid = tid >> 6;
    int m0 = blockIdx.y * 128, n0 = blockIdx.x * 128;
    int wm = (wid >> 1) * 64, wn = (wid & 1) * 64;
    int r16 = lane & 15, g = lane >> 4;
    int srow = tid >> 2, sch = (tid & 3) * 8;
    f32x4 acc[4][4] = {};
    for (int kb = 0; kb < K; kb += 32) {
        __syncthreads();
        *(bf16x8*)&Al[srow][sch]      = *(const bf16x8*)&A [(size_t)(m0 + srow) * K + kb + sch];
        *(bf16x8*)&Al[srow + 64][sch] = *(const bf16x8*)&A [(size_t)(m0 + srow + 64) * K + kb + sch];
        *(bf16x8*)&Bl[srow][sch]      = *(const bf16x8*)&Wt[(size_t)(n0 + srow) * K + kb + sch];
        *(bf16x8*)&Bl[srow + 64][sch] = *(const bf16x8*)&Wt[(size_t)(n0 + srow + 64) * K + kb + sch];
        __syncthreads();
        bf16x8 af[4], bfr[4];
        #pragma unroll
        for (int i = 0; i < 4; ++i) af[i]  = *(const bf16x8*)&Al[wm + i * 16 + r16][g * 8];
        #pragma unroll
        for (int j = 0; j < 4; ++j) bfr[j] = *(const bf16x8*)&Bl[wn + j * 16 + r16][g * 8];
        #pragma unroll
        for (int i = 0; i < 4; ++i)
            #pragma unroll
            for (int j = 0; j < 4; ++j)
                acc[i][j] = mfma16(af[i], bfr[j], acc[i][j]);
    }
    #pragma unroll
    for (int i = 0; i < 4; ++i) {
        #pragma unroll
        for (int j = 0; j < 4; ++j) {
            int n = n0 + wn + j * 16 + r16;
            float bv = bias[n];
            #pragma unroll
            for (int e = 0; e < 4; ++e) {
                int m = m0 + wm + i * 16 + g * 4 + e;
                float v = acc[i][j][e] + bv;
                if (MODE == 2) {
                    ((float*)outp)[(size_t)m * D_ + n] = v;
                } else {
                    int b = m >> 11, l = m & (L_ - 1);
                    int h = n >> 6, hd = n & 63;
                    bf16_t* o = (bf16_t*)outp;
                    if (MODE == 0)
                        o[(((size_t)(b * H_ + h)) * L_ + l) * HD_ + hd] = __float2bfloat16(v);
                    else
                        o[(((size_t)(b * H_ + h)) * HD_ + hd) * L_ + l] = __float2bfloat16(v);
                }
            }
        }
    }
}

// ---- fused causal attention v2 ----
// wave = 32 q-rows. 128-thr blocks (2 waves, 2 tasks). Heavy tiles first.
// Phase1: Z + unnormalized PV (K double-buffered, V issued at step top).
// Phase2: recompute scores with K prefetch, write normalized attn. Then zero-fill.
__global__ __launch_bounds__(128, 3) void k_attn(const bf16_t* __restrict__ Q,
                                                 const bf16_t* __restrict__ Kb,
                                                 const bf16_t* __restrict__ VT,
                                                 bf16_t* __restrict__ ctx,
                                                 float* __restrict__ attn) {
    __shared__ __align__(16) bf16_t plds[2][32][40];
    int tid = threadIdx.x, lane = tid & 63, wid = tid >> 6;
    int task = blockIdx.x * 2 + wid;
    int bh = task & 31;
    int qt = 63 - (task >> 5);          // heavy-first
    int b = bh >> 4, h = bh & 15;
    int qb = qt * 32;
    const int diag = qt;                // kt range 0..diag (32-key strips)
    const bf16_t* Qh = Q  + (size_t)bh * L_ * HD_;
    const bf16_t* Kh = Kb + (size_t)bh * L_ * HD_;
    const bf16_t* Vh = VT + (size_t)bh * HD_ * L_;
    int r16 = lane & 15, g = lane >> 4;
    const float scale = 0.125f;

    bf16x8 q[2][2];
    #pragma unroll
    for (int p = 0; p < 2; ++p)
        #pragma unroll
        for (int hh = 0; hh < 2; ++hh)
            q[p][hh] = *(const bf16x8*)&Qh[(qb + p * 16 + r16) * HD_ + hh * 32 + g * 8];

    f32x4 ctxa[2][4] = {};
    float zsum[2][4] = {};

    bf16x8 kA[2][2], kB[2][2];

    auto LK = [&](bf16x8 (&kf)[2][2], int kt) {
        const bf16_t* base = Kh + (size_t)kt * 32 * HD_;
        #pragma unroll
        for (int s = 0; s < 2; ++s)
            #pragma unroll
            for (int hh = 0; hh < 2; ++hh)
                kf[s][hh] = *(const bf16x8*)&base[(s * 16 + r16) * HD_ + hh * 32 + g * 8];
    };

    auto p1step = [&](bf16x8 (&KF)[2][2], bf16x8 (&KFN)[2][2], int kt) {
        bf16x8 vf[4];
        const bf16_t* vbase = Vh + kt * 32 + g * 8;
        #pragma unroll
        for (int t = 0; t < 4; ++t)
            vf[t] = *(const bf16x8*)&vbase[(size_t)(t * 16 + r16) * L_];
        f32x4 sa[2][2];
        #pragma unroll
        for (int p = 0; p < 2; ++p)
            #pragma unroll
            for (int s = 0; s < 2; ++s) {
                f32x4 zz = {};
                sa[p][s] = mfma16(q[p][1], KF[s][1], mfma16(q[p][0], KF[s][0], zz));
            }
        if (kt < diag) LK(KFN, kt + 1);
        int kb = kt * 32;
        #pragma unroll
        for (int p = 0; p < 2; ++p)
            #pragma unroll
            for (int s = 0; s < 2; ++s)
                #pragma unroll
                for (int e = 0; e < 4; ++e) {
                    int qrow = qb + p * 16 + g * 4 + e;
                    int key = kb + s * 16 + r16;
                    float sc = sa[p][s][e] * scale;
                    sc = fminf(fmaxf(sc, -50.f), 50.f);
                    float ev = (key > qrow) ? 0.f : __expf(sc);
                    zsum[p][e] += ev;
                    plds[wid][p * 16 + g * 4 + e][s * 16 + r16] = __float2bfloat16(ev);
                }
        #pragma unroll
        for (int p = 0; p < 2; ++p) {
            bf16x8 pa = *(const bf16x8*)&plds[wid][p * 16 + r16][g * 8];
            #pragma unroll
            for (int t = 0; t < 4; ++t)
                ctxa[p][t] = mfma16(pa, vf[t], ctxa[p][t]);
        }
    };

    LK(kA, 0);
    for (int kt = 0;;) {
        p1step(kA, kB, kt); if (++kt > diag) break;
        p1step(kB, kA, kt); if (++kt > diag) break;
    }

    // Z reduce across the 16 lanes of each row-group
    float invz[2][4];
    #pragma unroll
    for (int p = 0; p < 2; ++p)
        #pragma unroll
        for (int e = 0; e < 4; ++e) {
            float v = zsum[p][e];
            v += __shfl_xor(v, 1);
            v += __shfl_xor(v, 2);
            v += __shfl_xor(v, 4);
            v += __shfl_xor(v, 8);
            invz[p][e] = 1.f / v;
        }

    // normalized context -> ctx [B, L, D] bf16
    #pragma unroll
    for (int p = 0; p < 2; ++p)
        #pragma unroll
        for (int t = 0; t < 4; ++t)
            #pragma unroll
            for (int e = 0; e < 4; ++e) {
                int qrow = qb + p * 16 + g * 4 + e;
                int col = h * HD_ + t * 16 + r16;
                ctx[((size_t)b * L_ + qrow) * D_ + col] =
                    __float2bfloat16(ctxa[p][t][e] * invz[p][e]);
            }

    // phase 2: recompute scores, write normalized attn
    auto p2step = [&](bf16x8 (&KF)[2][2], bf16x8 (&KFN)[2][2], int kt) {
        f32x4 sa[2][2];
        #pragma unroll
        for (int p = 0; p < 2; ++p)
            #pragma unroll
            for (int s = 0; s < 2; ++s) {
                f32x4 zz = {};
                sa[p][s] = mfma16(q[p][1], KF[s][1], mfma16(q[p][0], KF[s][0], zz));
            }
        if (kt < diag) LK(KFN, kt + 1);
        int kb = kt * 32;
        #pragma unroll
        for (int p = 0; p < 2; ++p)
            #pragma unroll
            for (int s = 0; s < 2; ++s)
                #pragma unroll
                for (int e = 0; e < 4; ++e) {
                    int qrow = qb + p * 16 + g * 4 + e;
                    int key = kb + s * 16 + r16;
                    float sc = sa[p][s][e] * scale;
                    sc = fminf(fmaxf(sc, -50.f), 50.f);
                    float av = (key > qrow) ? 0.f : __expf(sc) * invz[p][e];
                    attn[((size_t)bh * L_ + qrow) * L_ + key] = av;
                }
    };

    LK(kA, 0);
    for (int kt = 0;;) {
        p2step(kA, kB, kt); if (++kt > diag) break;
        p2step(kB, kA, kt); if (++kt > diag) break;
    }

    // zero-fill fully-masked tail
    int zs = (qt + 1) * 32;
    if (zs < L_) {
        float4 z4 = make_float4(0.f, 0.f, 0.f, 0.f);
        for (int r = 0; r < 32; ++r) {
            float* rowp = attn + ((size_t)bh * L_ + qb + r) * L_;
            for (int c = zs + lane * 4; c < L_; c += 256)
                *(float4*)&rowp[c] = z4;
        }
    }
}

extern "C" void kernel_launch(void* const* d_in, const int* in_sizes, int n_in,
                              void* d_out, int out_size, void* d_ws, size_t ws_size,
                              hipStream_t stream) {
    const float* x  = (const float*)d_in[0];
    const float* wq = (const float*)d_in[1];
    const float* bq = (const float*)d_in[2];
    const float* wk = (const float*)d_in[3];
    const float* bk = (const float*)d_in[4];
    const float* wv = (const float*)d_in[5];
    const float* bv = (const float*)d_in[6];
    const float* wo = (const float*)d_in[7];
    const float* bo = (const float*)d_in[8];

    char* ws = (char*)d_ws;
    bf16_t* xb   = (bf16_t*)(ws);
    bf16_t* wqt  = (bf16_t*)(ws + ( 8u << 20));
    bf16_t* wkt  = (bf16_t*)(ws + (10u << 20));
    bf16_t* wvt  = (bf16_t*)(ws + (12u << 20));
    bf16_t* wot  = (bf16_t*)(ws + (14u << 20));
    bf16_t* Qb   = (bf16_t*)(ws + (16u << 20));
    bf16_t* Kbuf = (bf16_t*)(ws + (24u << 20));
    bf16_t* VTb  = (bf16_t*)(ws + (32u << 20));
    bf16_t* ctxb = (bf16_t*)(ws + (40u << 20));

    float* out  = (float*)d_out;
    float* attn = out + (size_t)B_ * L_ * D_;

    k_convert<<<2048, 256, 0, stream>>>(x, xb, (B_ * L_ * D_) / 8);
    dim3 tg(16, 16);
    k_transpose<<<tg, 256, 0, stream>>>(wq, wqt);
    k_transpose<<<tg, 256, 0, stream>>>(wk, wkt);
    k_transpose<<<tg, 256, 0, stream>>>(wv, wvt);
    k_transpose<<<tg, 256, 0, stream>>>(wo, wot);

    dim3 gg(D_ / 128, (B_ * L_) / 128);
    k_gemm<0><<<gg, 256, 0, stream>>>(xb, wqt, bq, Qb);
    k_gemm<0><<<gg, 256, 0, stream>>>(xb, wkt, bk, Kbuf);
    k_gemm<1><<<gg, 256, 0, stream>>>(xb, wvt, bv, VTb);

    k_attn<<<1024, 128, 0, stream>>>(Qb, Kbuf, VTb, ctxb, attn);

    k_gemm<2><<<gg, 256, 0, stream>>>(ctxb, wot, bo, d_out);
}